// Round 10
// baseline (123.115 us; speedup 1.0000x reference)
//
#include <hip/hip_runtime.h>
#include <cstdint>
#include <cstddef>

#define NB 8
#define NS 4096
#define NN 2048
#define NH 768
#define NK 50

// ---------------------------------------------------------------------------
// KD: rowdot[b][c][s] = dot(x[b,s,:], anchor[c,:]). [UNCHANGED from R7-R9]
// ---------------------------------------------------------------------------
__global__ __launch_bounds__(256) void kd_rowdots(const float* __restrict__ x,
                                                  const float* __restrict__ anchor,
                                                  float* __restrict__ rowdot) {
  const int lane = threadIdx.x & 63;
  const int gw   = blockIdx.x * 4 + (threadIdx.x >> 6);   // 0..4095

  float4 a[3][3];
#pragma unroll
  for (int c = 0; c < 3; ++c)
#pragma unroll
    for (int p = 0; p < 3; ++p)
      a[c][p] = *reinterpret_cast<const float4*>(anchor + c * NH + p * 256 + lane * 4);

  const float* base = x + (size_t)gw * 8 * NH + lane * 4;

  float4 va[3], vb[3];
#pragma unroll
  for (int p = 0; p < 3; ++p)
    va[p] = *reinterpret_cast<const float4*>(base + p * 256);

#define KD_LOAD(V, I)                                                         \
  {                                                                           \
    const float* s_ = base + (size_t)(I) * NH;                                \
    _Pragma("unroll")                                                         \
    for (int p = 0; p < 3; ++p)                                               \
      V[p] = *reinterpret_cast<const float4*>(s_ + p * 256);                  \
  }
#define KD_CONS(V, I)                                                         \
  {                                                                           \
    float d0 = 0.f, d1 = 0.f, d2 = 0.f;                                       \
    _Pragma("unroll")                                                         \
    for (int p = 0; p < 3; ++p) {                                             \
      d0 += V[p].x * a[0][p].x + V[p].y * a[0][p].y +                         \
            V[p].z * a[0][p].z + V[p].w * a[0][p].w;                          \
      d1 += V[p].x * a[1][p].x + V[p].y * a[1][p].y +                         \
            V[p].z * a[1][p].z + V[p].w * a[1][p].w;                          \
      d2 += V[p].x * a[2][p].x + V[p].y * a[2][p].y +                         \
            V[p].z * a[2][p].z + V[p].w * a[2][p].w;                          \
    }                                                                         \
    _Pragma("unroll")                                                         \
    for (int o = 32; o > 0; o >>= 1) {                                        \
      d0 += __shfl_xor(d0, o);                                                \
      d1 += __shfl_xor(d1, o);                                                \
      d2 += __shfl_xor(d2, o);                                                \
    }                                                                         \
    if (lane == 0) {                                                          \
      int r = gw * 8 + (I);                                                   \
      int b = r >> 12, s = r & 4095;                                          \
      float* o_ = rowdot + (size_t)b * 3 * NS + s;                            \
      o_[0]      = d0;                                                        \
      o_[NS]     = d1;                                                        \
      o_[2 * NS] = d2;                                                        \
    }                                                                         \
  }

#pragma unroll
  for (int i = 0; i < 8; i += 2) {
    KD_LOAD(vb, i + 1)
    KD_CONS(va, i)
    if (i + 2 < 8) KD_LOAD(va, i + 2)
    KD_CONS(vb, i + 1)
  }
#undef KD_LOAD
#undef KD_CONS
}

// ---------------------------------------------------------------------------
// KF: fully fused per-batch tail: span scores -> radix-2 top-50 -> 48-way
// projections (LDS) -> 50x50x5 epilogue. One 1024-thread block per batch.
// Scores/selection bitwise-identical to R9; proj per-wave body identical to
// R9's k4a (same lane layout); epilogue arithmetic identical to R9's k4b.
// topidx and proj never touch global memory.
// ---------------------------------------------------------------------------
__global__ __launch_bounds__(1024) void kf_tail(const float* __restrict__ x,
                                                const float* __restrict__ rowdot,
                                                const int* __restrict__ starts,
                                                const int* __restrict__ lens,
                                                const float* __restrict__ rel,
                                                const float* __restrict__ nota,
                                                float* __restrict__ out) {
  const int b    = blockIdx.x;
  const int tid  = threadIdx.x;
  const int wid  = tid >> 6;
  const int lane = tid & 63;

  __shared__ unsigned long long wred[16];
  __shared__ unsigned long long cand[NN];
  __shared__ unsigned candcnt;
  __shared__ int   topidx[NK];
  __shared__ float proj[NK][48];

  // ---- span scores (bitwise-identical to R9) ----
  unsigned long long key0, key1;
#pragma unroll
  for (int half = 0; half < 2; ++half) {
    const int sp = tid + half * 1024;
    const int st = starts[b * NN + sp];
    const int n  = lens[b * NN + sp] + 1;
    const float* rd = rowdot + (size_t)b * 3 * NS + st;
    float s0 = 0.f, s1 = 0.f, s2 = 0.f;
    for (int r = 0; r < n; ++r) {
      s0 += rd[r];
      s1 += rd[NS + r];
      s2 += rd[2 * NS + r];
    }
    float sc = fmaxf(s0, fmaxf(s1, s2)) / (float)n;
    unsigned u   = __float_as_uint(sc);
    unsigned ord = (u & 0x80000000u) ? ~u : (u | 0x80000000u);
    unsigned long long k = ((unsigned long long)ord << 32) | (unsigned)(NN - 1 - sp);
    if (half == 0) key0 = k; else key1 = k;
  }
  const unsigned ord0 = (unsigned)(key0 >> 32);
  const unsigned ord1 = (unsigned)(key1 >> 32);

  // ---- radix-2 MSB-first select: T = ord of the 50th-largest key ----
  unsigned T = 0;
  int rem = NK;
  bool a0 = true, a1 = true;
  for (int bit = 30; bit >= 0; bit -= 2) {
    const int u0 = a0 ? (int)((ord0 >> bit) & 3) : -1;
    const int u1 = a1 ? (int)((ord1 >> bit) & 3) : -1;
    unsigned c3 = __popcll(__ballot(u0 == 3)) + __popcll(__ballot(u1 == 3));
    unsigned c2 = __popcll(__ballot(u0 == 2)) + __popcll(__ballot(u1 == 2));
    unsigned c1 = __popcll(__ballot(u0 == 1)) + __popcll(__ballot(u1 == 1));
    if (lane == 0)
      wred[wid] = ((unsigned long long)c3 << 28) |
                  ((unsigned long long)c2 << 14) | c1;
    __syncthreads();
    unsigned long long s = 0;
#pragma unroll
    for (int i = 0; i < 16; ++i) s += wred[i];
    __syncthreads();
    const int C3 = (int)((s >> 28) & 0x3FFF);
    const int C2 = (int)((s >> 14) & 0x3FFF);
    const int C1 = (int)(s & 0x3FFF);
    int d;
    if (C3 >= rem)                 d = 3;
    else if (C3 + C2 >= rem)      { d = 2; rem -= C3; }
    else if (C3 + C2 + C1 >= rem) { d = 1; rem -= C3 + C2; }
    else                          { d = 0; rem -= C3 + C2 + C1; }
    T |= ((unsigned)d) << bit;
    a0 = a0 && (u0 == d);
    a1 = a1 && (u1 == d);
  }

  // ---- compact candidates (ord >= T), exact rank, store topidx to LDS ----
  if (tid == 0) candcnt = 0;
  __syncthreads();
  if (ord0 >= T) { unsigned p = atomicAdd(&candcnt, 1u); cand[p] = key0; }
  if (ord1 >= T) { unsigned p = atomicAdd(&candcnt, 1u); cand[p] = key1; }
  __syncthreads();
  const int M = (int)candcnt;
  for (int i = tid; i < M; i += 1024) {
    const unsigned long long ki = cand[i];
    int r = 0;
    for (int j = 0; j < M; ++j) r += (cand[j] > ki);
    if (r < NK)
      topidx[r] = (NN - 1) - (int)(ki & 0xFFFFFFFFull);
  }
  __syncthreads();

  // ---- projections (identical per-wave body to R9's k4a); wave w takes
  //      spans w, w+16, w+32 ----
  for (int k = wid; k < NK; k += 16) {
    const int n  = topidx[k];
    const int st = starts[b * NN + n];
    const int nt = lens[b * NN + n] + 1;
    const float fnt = (float)nt;

    float4 e[3];
#pragma unroll
    for (int p = 0; p < 3; ++p) { e[p].x = 0.f; e[p].y = 0.f; e[p].z = 0.f; e[p].w = 0.f; }
    for (int r = 0; r < nt; ++r) {
      const float* row = x + ((size_t)b * NS + st + r) * NH + lane * 4;
#pragma unroll
      for (int p = 0; p < 3; ++p) {
        float4 v = *reinterpret_cast<const float4*>(row + p * 256);
        e[p].x += v.x; e[p].y += v.y; e[p].z += v.z; e[p].w += v.w;
      }
    }
#pragma unroll
    for (int p = 0; p < 3; ++p) {
      e[p].x /= fnt; e[p].y /= fnt; e[p].z /= fnt; e[p].w /= fnt;
    }

    for (int w = 0; w < 48; ++w) {
      const float* wr;
      if (w < 4)       wr = rel  + (size_t)w * (2 * NH);
      else if (w < 8)  wr = rel  + (size_t)(w - 4) * (2 * NH) + NH;
      else if (w < 28) wr = nota + (size_t)(w - 8) * (2 * NH);
      else             wr = nota + (size_t)(w - 28) * (2 * NH) + NH;
      wr += lane * 4;
      float d = 0.f;
#pragma unroll
      for (int p = 0; p < 3; ++p) {
        float4 wv = *reinterpret_cast<const float4*>(wr + p * 256);
        d += e[p].x * wv.x + e[p].y * wv.y + e[p].z * wv.z + e[p].w * wv.w;
      }
#pragma unroll
      for (int o = 32; o > 0; o >>= 1) d += __shfl_xor(d, o);
      if (lane == 0) proj[k][w] = d;
    }
  }
  __syncthreads();

  // ---- epilogue (identical arithmetic to R9's k4b) ----
  for (int idx = tid; idx < NK * NK; idx += 1024) {
    const int k1 = idx / NK, k2 = idx % NK;
    const float* p1 = proj[k1];
    const float* p2 = proj[k2];
    float mx = p1[8] + p2[28];
#pragma unroll
    for (int m = 1; m < 20; ++m) mx = fmaxf(mx, p1[8 + m] + p2[28 + m]);
    float* o = out + ((size_t)b * NK * NK + idx) * 5;
    o[0] = mx;
#pragma unroll
    for (int r = 0; r < 4; ++r) o[1 + r] = p1[r] + p2[4 + r];
  }
}

// ---------------------------------------------------------------------------
extern "C" void kernel_launch(void* const* d_in, const int* in_sizes, int n_in,
                              void* d_out, int out_size, void* d_ws, size_t ws_size,
                              hipStream_t stream) {
  const float* x      = (const float*)d_in[0];
  const int*   starts = (const int*)d_in[1];
  const int*   lens   = (const int*)d_in[2];
  const float* anchor = (const float*)d_in[3];
  const float* rel    = (const float*)d_in[4];
  const float* nota   = (const float*)d_in[5];
  float* out = (float*)d_out;

  float* rowdot = (float*)d_ws;                                  // 1.5 MB

  hipLaunchKernelGGL(kd_rowdots, dim3(1024), dim3(256), 0, stream, x, anchor, rowdot);
  hipLaunchKernelGGL(kf_tail, dim3(NB), dim3(1024), 0, stream,
                     x, rowdot, starts, lens, rel, nota, out);
}

// Round 11
// 60.556 us; speedup vs baseline: 2.0331x; 2.0331x over previous
//
#include <hip/hip_runtime.h>
#include <cstdint>
#include <cstddef>

#define NB 8
#define NS 4096
#define NN 2048
#define NH 768
#define NK 50

// ---------------------------------------------------------------------------
// KD: rowdot[b][c][s] = dot(x[b,s,:], anchor[c,:]). [UNCHANGED from R7-R9]
// ---------------------------------------------------------------------------
__global__ __launch_bounds__(256) void kd_rowdots(const float* __restrict__ x,
                                                  const float* __restrict__ anchor,
                                                  float* __restrict__ rowdot) {
  const int lane = threadIdx.x & 63;
  const int gw   = blockIdx.x * 4 + (threadIdx.x >> 6);   // 0..4095

  float4 a[3][3];
#pragma unroll
  for (int c = 0; c < 3; ++c)
#pragma unroll
    for (int p = 0; p < 3; ++p)
      a[c][p] = *reinterpret_cast<const float4*>(anchor + c * NH + p * 256 + lane * 4);

  const float* base = x + (size_t)gw * 8 * NH + lane * 4;

  float4 va[3], vb[3];
#pragma unroll
  for (int p = 0; p < 3; ++p)
    va[p] = *reinterpret_cast<const float4*>(base + p * 256);

#define KD_LOAD(V, I)                                                         \
  {                                                                           \
    const float* s_ = base + (size_t)(I) * NH;                                \
    _Pragma("unroll")                                                         \
    for (int p = 0; p < 3; ++p)                                               \
      V[p] = *reinterpret_cast<const float4*>(s_ + p * 256);                  \
  }
#define KD_CONS(V, I)                                                         \
  {                                                                           \
    float d0 = 0.f, d1 = 0.f, d2 = 0.f;                                       \
    _Pragma("unroll")                                                         \
    for (int p = 0; p < 3; ++p) {                                             \
      d0 += V[p].x * a[0][p].x + V[p].y * a[0][p].y +                         \
            V[p].z * a[0][p].z + V[p].w * a[0][p].w;                          \
      d1 += V[p].x * a[1][p].x + V[p].y * a[1][p].y +                         \
            V[p].z * a[1][p].z + V[p].w * a[1][p].w;                          \
      d2 += V[p].x * a[2][p].x + V[p].y * a[2][p].y +                         \
            V[p].z * a[2][p].z + V[p].w * a[2][p].w;                          \
    }                                                                         \
    _Pragma("unroll")                                                         \
    for (int o = 32; o > 0; o >>= 1) {                                        \
      d0 += __shfl_xor(d0, o);                                                \
      d1 += __shfl_xor(d1, o);                                                \
      d2 += __shfl_xor(d2, o);                                                \
    }                                                                         \
    if (lane == 0) {                                                          \
      int r = gw * 8 + (I);                                                   \
      int b = r >> 12, s = r & 4095;                                          \
      float* o_ = rowdot + (size_t)b * 3 * NS + s;                            \
      o_[0]      = d0;                                                        \
      o_[NS]     = d1;                                                        \
      o_[2 * NS] = d2;                                                        \
    }                                                                         \
  }

#pragma unroll
  for (int i = 0; i < 8; i += 2) {
    KD_LOAD(vb, i + 1)
    KD_CONS(va, i)
    if (i + 2 < 8) KD_LOAD(va, i + 2)
    KD_CONS(vb, i + 1)
  }
#undef KD_LOAD
#undef KD_CONS
}

// ---------------------------------------------------------------------------
// K3F: span scores + top-50 via radix-2 rank-select.  Changes vs R9 (both
// selection-bit-exact):
//  - score loop de-ragged: always load 8 rows (st <= S-9 guarantees bounds),
//    accumulate via select s=(r<n)?s+v:s  -> identical add sequence, but
//    loads pipeline instead of serializing behind a divergent loop.
//  - radix iteration: per-iteration pre-zeroed LDS counter slots; wave
//    lane-0s atomicAdd ballot counts; ONE barrier/iter; every thread reads
//    the 3 broadcast words and derives the digit locally (exact counts ->
//    identical T, rem sequence).
// ---------------------------------------------------------------------------
__global__ __launch_bounds__(1024) void k3f_topk(const float* __restrict__ rowdot,
                                                 const int* __restrict__ starts,
                                                 const int* __restrict__ lens,
                                                 int* __restrict__ topidx) {
  const int b    = blockIdx.x;
  const int tid  = threadIdx.x;
  const int lane = tid & 63;

  __shared__ unsigned cnt[16][4];          // per-iteration digit counts
  __shared__ unsigned long long cand[NN];
  __shared__ unsigned candcnt;

  if (tid < 64) cnt[tid >> 2][tid & 3] = 0u;
  if (tid == 64) candcnt = 0u;

  // ---- span scores (bit-identical to R9: same adds, same order) ----
  unsigned long long key0, key1;
#pragma unroll
  for (int half = 0; half < 2; ++half) {
    const int sp = tid + half * 1024;
    const int st = starts[b * NN + sp];
    const int n  = lens[b * NN + sp] + 1;
    const float* rd = rowdot + (size_t)b * 3 * NS + st;
    float v0[8], v1[8], v2[8];
#pragma unroll
    for (int r = 0; r < 8; ++r) {          // st+7 <= 4094 < NS: always safe
      v0[r] = rd[r];
      v1[r] = rd[NS + r];
      v2[r] = rd[2 * NS + r];
    }
    float s0 = 0.f, s1 = 0.f, s2 = 0.f;
#pragma unroll
    for (int r = 0; r < 8; ++r) {
      const bool c = r < n;
      const float t0 = s0 + v0[r], t1 = s1 + v1[r], t2 = s2 + v2[r];
      s0 = c ? t0 : s0; s1 = c ? t1 : s1; s2 = c ? t2 : s2;
    }
    float sc = fmaxf(s0, fmaxf(s1, s2)) / (float)n;
    unsigned u   = __float_as_uint(sc);
    unsigned ord = (u & 0x80000000u) ? ~u : (u | 0x80000000u);
    unsigned long long k = ((unsigned long long)ord << 32) | (unsigned)(NN - 1 - sp);
    if (half == 0) key0 = k; else key1 = k;
  }
  const unsigned ord0 = (unsigned)(key0 >> 32);
  const unsigned ord1 = (unsigned)(key1 >> 32);
  __syncthreads();                         // cnt/candcnt zeroed; scores ready

  // ---- radix-2 MSB-first select: T = ord of the 50th-largest key ----
  unsigned T = 0;
  int rem = NK;
  bool a0 = true, a1 = true;
#pragma unroll
  for (int it = 0; it < 16; ++it) {
    const int bit = 30 - 2 * it;
    const int u0 = a0 ? (int)((ord0 >> bit) & 3) : -1;
    const int u1 = a1 ? (int)((ord1 >> bit) & 3) : -1;
    const unsigned c3 = __popcll(__ballot(u0 == 3)) + __popcll(__ballot(u1 == 3));
    const unsigned c2 = __popcll(__ballot(u0 == 2)) + __popcll(__ballot(u1 == 2));
    const unsigned c1 = __popcll(__ballot(u0 == 1)) + __popcll(__ballot(u1 == 1));
    if (lane == 0) {
      if (c3) atomicAdd(&cnt[it][3], c3);
      if (c2) atomicAdd(&cnt[it][2], c2);
      if (c1) atomicAdd(&cnt[it][1], c1);
    }
    __syncthreads();
    const int C3 = (int)cnt[it][3];
    const int C2 = (int)cnt[it][2];
    const int C1 = (int)cnt[it][1];
    int d;
    if (C3 >= rem)                 d = 3;
    else if (C3 + C2 >= rem)      { d = 2; rem -= C3; }
    else if (C3 + C2 + C1 >= rem) { d = 1; rem -= C3 + C2; }
    else                          { d = 0; rem -= C3 + C2 + C1; }
    T |= ((unsigned)d) << bit;
    a0 = a0 && (u0 == d);
    a1 = a1 && (u1 == d);
  }

  // ---- compact candidates (ord >= T), exact rank, emit ----
  if (ord0 >= T) { unsigned p = atomicAdd(&candcnt, 1u); cand[p] = key0; }
  if (ord1 >= T) { unsigned p = atomicAdd(&candcnt, 1u); cand[p] = key1; }
  __syncthreads();
  const int M = (int)candcnt;
  for (int i = tid; i < M; i += 1024) {
    const unsigned long long ki = cand[i];
    int r = 0;
    for (int j = 0; j < M; ++j) r += (cand[j] > ki);
    if (r < NK)
      topidx[b * NK + r] = (NN - 1) - (int)(ki & 0xFFFFFFFFull);
  }
}

// ---------------------------------------------------------------------------
// K4a: projections for the 400 selected spans. [UNCHANGED = R9]
// ---------------------------------------------------------------------------
__global__ __launch_bounds__(256) void k4a_proj(const float* __restrict__ x,
                                                const int* __restrict__ starts,
                                                const int* __restrict__ lens,
                                                const int* __restrict__ topidx,
                                                const float* __restrict__ rel,
                                                const float* __restrict__ nota,
                                                float* __restrict__ proj) {
  const int gw   = blockIdx.x * 4 + (threadIdx.x >> 6);   // 0..399
  const int lane = threadIdx.x & 63;
  const int b = gw / NK, k = gw % NK;
  const int n  = topidx[b * NK + k];
  const int st = starts[b * NN + n];
  const int nt = lens[b * NN + n] + 1;
  const float fnt = (float)nt;

  float4 e[3];
#pragma unroll
  for (int p = 0; p < 3; ++p) { e[p].x = 0.f; e[p].y = 0.f; e[p].z = 0.f; e[p].w = 0.f; }
  for (int r = 0; r < nt; ++r) {
    const float* row = x + ((size_t)b * NS + st + r) * NH + lane * 4;
#pragma unroll
    for (int p = 0; p < 3; ++p) {
      float4 v = *reinterpret_cast<const float4*>(row + p * 256);
      e[p].x += v.x; e[p].y += v.y; e[p].z += v.z; e[p].w += v.w;
    }
  }
#pragma unroll
  for (int p = 0; p < 3; ++p) {
    e[p].x /= fnt; e[p].y /= fnt; e[p].z /= fnt; e[p].w /= fnt;
  }

  for (int w = 0; w < 48; ++w) {
    const float* wr;
    if (w < 4)       wr = rel  + (size_t)w * (2 * NH);
    else if (w < 8)  wr = rel  + (size_t)(w - 4) * (2 * NH) + NH;
    else if (w < 28) wr = nota + (size_t)(w - 8) * (2 * NH);
    else             wr = nota + (size_t)(w - 28) * (2 * NH) + NH;
    wr += lane * 4;
    float d = 0.f;
#pragma unroll
    for (int p = 0; p < 3; ++p) {
      float4 wv = *reinterpret_cast<const float4*>(wr + p * 256);
      d += e[p].x * wv.x + e[p].y * wv.y + e[p].z * wv.z + e[p].w * wv.w;
    }
#pragma unroll
    for (int o = 32; o > 0; o >>= 1) d += __shfl_xor(d, o);
    if (lane == 0) proj[((size_t)b * NK + k) * 48 + w] = d;
  }
}

// ---------------------------------------------------------------------------
// K4b: epilogue. [UNCHANGED = R9]
// ---------------------------------------------------------------------------
__global__ __launch_bounds__(256) void k4b_out(const float* __restrict__ proj,
                                               float* __restrict__ out) {
  int idx = blockIdx.x * 256 + threadIdx.x;
  if (idx >= NB * NK * NK) return;
  int b  = idx / (NK * NK);
  int rr = idx % (NK * NK);
  int k1 = rr / NK, k2 = rr % NK;
  const float* p1 = proj + ((size_t)b * NK + k1) * 48;
  const float* p2 = proj + ((size_t)b * NK + k2) * 48;
  float mx = p1[8] + p2[28];
#pragma unroll
  for (int m = 1; m < 20; ++m) mx = fmaxf(mx, p1[8 + m] + p2[28 + m]);
  float* o = out + (size_t)idx * 5;
  o[0] = mx;
#pragma unroll
  for (int r = 0; r < 4; ++r) o[1 + r] = p1[r] + p2[4 + r];
}

// ---------------------------------------------------------------------------
extern "C" void kernel_launch(void* const* d_in, const int* in_sizes, int n_in,
                              void* d_out, int out_size, void* d_ws, size_t ws_size,
                              hipStream_t stream) {
  const float* x      = (const float*)d_in[0];
  const int*   starts = (const int*)d_in[1];
  const int*   lens   = (const int*)d_in[2];
  const float* anchor = (const float*)d_in[3];
  const float* rel    = (const float*)d_in[4];
  const float* nota   = (const float*)d_in[5];
  float* out = (float*)d_out;

  char* ws = (char*)d_ws;
  float* rowdot = (float*)ws;                                    // 1.5 MB
  int*   topidx = (int*)(ws + (size_t)NB * 3 * NS * sizeof(float));
  float* proj   = (float*)(ws + (size_t)NB * 3 * NS * sizeof(float) + 4096);

  hipLaunchKernelGGL(kd_rowdots, dim3(1024), dim3(256), 0, stream, x, anchor, rowdot);
  hipLaunchKernelGGL(k3f_topk, dim3(NB), dim3(1024), 0, stream,
                     rowdot, starts, lens, topidx);
  hipLaunchKernelGGL(k4a_proj, dim3(NB * NK / 4), dim3(256), 0, stream,
                     x, starts, lens, topidx, rel, nota, proj);
  hipLaunchKernelGGL(k4b_out, dim3((NB * NK * NK + 255) / 256), dim3(256), 0, stream,
                     proj, out);
}

// Round 12
// 42.970 us; speedup vs baseline: 2.8652x; 1.4093x over previous
//
#include <hip/hip_runtime.h>
#include <cstdint>
#include <cstddef>

#define NB 8
#define NS 4096
#define NN 2048
#define NH 768
#define NK 50

// ---------------------------------------------------------------------------
// KD: rowdot[b][s][c] = dot(x[b,s,:], anchor[c,:]).  Same compute as R7-R11
// (bit-exact); store layout now interleaved [b][s][3] so consumers read one
// contiguous 12B run per row (and k3f gets 96B/thread contiguous).
// ---------------------------------------------------------------------------
__global__ __launch_bounds__(256) void kd_rowdots(const float* __restrict__ x,
                                                  const float* __restrict__ anchor,
                                                  float* __restrict__ rowdot) {
  const int lane = threadIdx.x & 63;
  const int gw   = blockIdx.x * 4 + (threadIdx.x >> 6);   // 0..4095

  float4 a[3][3];
#pragma unroll
  for (int c = 0; c < 3; ++c)
#pragma unroll
    for (int p = 0; p < 3; ++p)
      a[c][p] = *reinterpret_cast<const float4*>(anchor + c * NH + p * 256 + lane * 4);

  const float* base = x + (size_t)gw * 8 * NH + lane * 4;

  float4 va[3], vb[3];
#pragma unroll
  for (int p = 0; p < 3; ++p)
    va[p] = *reinterpret_cast<const float4*>(base + p * 256);

#define KD_LOAD(V, I)                                                         \
  {                                                                           \
    const float* s_ = base + (size_t)(I) * NH;                                \
    _Pragma("unroll")                                                         \
    for (int p = 0; p < 3; ++p)                                               \
      V[p] = *reinterpret_cast<const float4*>(s_ + p * 256);                  \
  }
#define KD_CONS(V, I)                                                         \
  {                                                                           \
    float d0 = 0.f, d1 = 0.f, d2 = 0.f;                                       \
    _Pragma("unroll")                                                         \
    for (int p = 0; p < 3; ++p) {                                             \
      d0 += V[p].x * a[0][p].x + V[p].y * a[0][p].y +                         \
            V[p].z * a[0][p].z + V[p].w * a[0][p].w;                          \
      d1 += V[p].x * a[1][p].x + V[p].y * a[1][p].y +                         \
            V[p].z * a[1][p].z + V[p].w * a[1][p].w;                          \
      d2 += V[p].x * a[2][p].x + V[p].y * a[2][p].y +                         \
            V[p].z * a[2][p].z + V[p].w * a[2][p].w;                          \
    }                                                                         \
    _Pragma("unroll")                                                         \
    for (int o = 32; o > 0; o >>= 1) {                                        \
      d0 += __shfl_xor(d0, o);                                                \
      d1 += __shfl_xor(d1, o);                                                \
      d2 += __shfl_xor(d2, o);                                                \
    }                                                                         \
    if (lane == 0) {                                                          \
      int r = gw * 8 + (I);                                                   \
      float* o_ = rowdot + (size_t)r * 3;                                     \
      o_[0] = d0; o_[1] = d1; o_[2] = d2;                                     \
    }                                                                         \
  }

#pragma unroll
  for (int i = 0; i < 8; i += 2) {
    KD_LOAD(vb, i + 1)
    KD_CONS(va, i)
    if (i + 2 < 8) KD_LOAD(va, i + 2)
    KD_CONS(vb, i + 1)
  }
#undef KD_LOAD
#undef KD_CONS
}

// ---------------------------------------------------------------------------
// K3F: span scores + top-50 via radix-2 rank-select. Same as R11 except the
// score read uses the interleaved rowdot layout (96B contiguous per thread).
// Score adds in identical order -> selection bit-exact.
// ---------------------------------------------------------------------------
__global__ __launch_bounds__(1024) void k3f_topk(const float* __restrict__ rowdot,
                                                 const int* __restrict__ starts,
                                                 const int* __restrict__ lens,
                                                 int* __restrict__ topidx) {
  const int b    = blockIdx.x;
  const int tid  = threadIdx.x;
  const int lane = tid & 63;

  __shared__ unsigned cnt[16][4];
  __shared__ unsigned long long cand[NN];
  __shared__ unsigned candcnt;

  if (tid < 64) cnt[tid >> 2][tid & 3] = 0u;
  if (tid == 64) candcnt = 0u;

  // ---- span scores ----
  unsigned long long key0, key1;
#pragma unroll
  for (int half = 0; half < 2; ++half) {
    const int sp = tid + half * 1024;
    const int st = starts[b * NN + sp];
    const int n  = lens[b * NN + sp] + 1;
    const float* rd = rowdot + ((size_t)b * NS + st) * 3;
    float v0[8], v1[8], v2[8];
#pragma unroll
    for (int r = 0; r < 8; ++r) {          // st+7 <= 4094 < NS: always safe
      v0[r] = rd[r * 3];
      v1[r] = rd[r * 3 + 1];
      v2[r] = rd[r * 3 + 2];
    }
    float s0 = 0.f, s1 = 0.f, s2 = 0.f;
#pragma unroll
    for (int r = 0; r < 8; ++r) {
      const bool c = r < n;
      const float t0 = s0 + v0[r], t1 = s1 + v1[r], t2 = s2 + v2[r];
      s0 = c ? t0 : s0; s1 = c ? t1 : s1; s2 = c ? t2 : s2;
    }
    float sc = fmaxf(s0, fmaxf(s1, s2)) / (float)n;
    unsigned u   = __float_as_uint(sc);
    unsigned ord = (u & 0x80000000u) ? ~u : (u | 0x80000000u);
    unsigned long long k = ((unsigned long long)ord << 32) | (unsigned)(NN - 1 - sp);
    if (half == 0) key0 = k; else key1 = k;
  }
  const unsigned ord0 = (unsigned)(key0 >> 32);
  const unsigned ord1 = (unsigned)(key1 >> 32);
  __syncthreads();

  // ---- radix-2 MSB-first select ----
  unsigned T = 0;
  int rem = NK;
  bool a0 = true, a1 = true;
#pragma unroll
  for (int it = 0; it < 16; ++it) {
    const int bit = 30 - 2 * it;
    const int u0 = a0 ? (int)((ord0 >> bit) & 3) : -1;
    const int u1 = a1 ? (int)((ord1 >> bit) & 3) : -1;
    const unsigned c3 = __popcll(__ballot(u0 == 3)) + __popcll(__ballot(u1 == 3));
    const unsigned c2 = __popcll(__ballot(u0 == 2)) + __popcll(__ballot(u1 == 2));
    const unsigned c1 = __popcll(__ballot(u0 == 1)) + __popcll(__ballot(u1 == 1));
    if (lane == 0) {
      if (c3) atomicAdd(&cnt[it][3], c3);
      if (c2) atomicAdd(&cnt[it][2], c2);
      if (c1) atomicAdd(&cnt[it][1], c1);
    }
    __syncthreads();
    const int C3 = (int)cnt[it][3];
    const int C2 = (int)cnt[it][2];
    const int C1 = (int)cnt[it][1];
    int d;
    if (C3 >= rem)                 d = 3;
    else if (C3 + C2 >= rem)      { d = 2; rem -= C3; }
    else if (C3 + C2 + C1 >= rem) { d = 1; rem -= C3 + C2; }
    else                          { d = 0; rem -= C3 + C2 + C1; }
    T |= ((unsigned)d) << bit;
    a0 = a0 && (u0 == d);
    a1 = a1 && (u1 == d);
  }

  // ---- compact candidates, exact rank, emit ----
  if (ord0 >= T) { unsigned p = atomicAdd(&candcnt, 1u); cand[p] = key0; }
  if (ord1 >= T) { unsigned p = atomicAdd(&candcnt, 1u); cand[p] = key1; }
  __syncthreads();
  const int M = (int)candcnt;
  for (int i = tid; i < M; i += 1024) {
    const unsigned long long ki = cand[i];
    int r = 0;
    for (int j = 0; j < M; ++j) r += (cand[j] > ki);
    if (r < NK)
      topidx[b * NK + r] = (NN - 1) - (int)(ki & 0xFFFFFFFFull);
  }
}

// ---------------------------------------------------------------------------
// K4a: projections. 400 blocks x 4 waves; every wave of block (b,k) computes
// the SAME emb (identical per-lane add order -> bit-identical to R11), then
// handles 12 of the 48 weight dots: serial chain / 4, all CUs covered.
// ---------------------------------------------------------------------------
__global__ __launch_bounds__(256) void k4a_proj(const float* __restrict__ x,
                                                const int* __restrict__ starts,
                                                const int* __restrict__ lens,
                                                const int* __restrict__ topidx,
                                                const float* __restrict__ rel,
                                                const float* __restrict__ nota,
                                                float* __restrict__ proj) {
  const int blk  = blockIdx.x;              // 0..399 = b*NK + k
  const int wid  = threadIdx.x >> 6;        // 0..3
  const int lane = threadIdx.x & 63;
  const int b = blk / NK, k = blk % NK;
  const int n  = topidx[b * NK + k];
  const int st = starts[b * NN + n];
  const int nt = lens[b * NN + n] + 1;
  const float fnt = (float)nt;

  float4 e[3];
#pragma unroll
  for (int p = 0; p < 3; ++p) { e[p].x = 0.f; e[p].y = 0.f; e[p].z = 0.f; e[p].w = 0.f; }
  for (int r = 0; r < nt; ++r) {
    const float* row = x + ((size_t)b * NS + st + r) * NH + lane * 4;
#pragma unroll
    for (int p = 0; p < 3; ++p) {
      float4 v = *reinterpret_cast<const float4*>(row + p * 256);
      e[p].x += v.x; e[p].y += v.y; e[p].z += v.z; e[p].w += v.w;
    }
  }
#pragma unroll
  for (int p = 0; p < 3; ++p) {
    e[p].x /= fnt; e[p].y /= fnt; e[p].z /= fnt; e[p].w /= fnt;
  }

#pragma unroll
  for (int j = 0; j < 12; ++j) {
    const int w = wid * 12 + j;
    const float* wr;
    if (w < 4)       wr = rel  + (size_t)w * (2 * NH);
    else if (w < 8)  wr = rel  + (size_t)(w - 4) * (2 * NH) + NH;
    else if (w < 28) wr = nota + (size_t)(w - 8) * (2 * NH);
    else             wr = nota + (size_t)(w - 28) * (2 * NH) + NH;
    wr += lane * 4;
    float d = 0.f;
#pragma unroll
    for (int p = 0; p < 3; ++p) {
      float4 wv = *reinterpret_cast<const float4*>(wr + p * 256);
      d += e[p].x * wv.x + e[p].y * wv.y + e[p].z * wv.z + e[p].w * wv.w;
    }
#pragma unroll
    for (int o = 32; o > 0; o >>= 1) d += __shfl_xor(d, o);
    if (lane == 0) proj[((size_t)b * NK + k) * 48 + w] = d;
  }
}

// ---------------------------------------------------------------------------
// K4b: epilogue. [UNCHANGED]
// ---------------------------------------------------------------------------
__global__ __launch_bounds__(256) void k4b_out(const float* __restrict__ proj,
                                               float* __restrict__ out) {
  int idx = blockIdx.x * 256 + threadIdx.x;
  if (idx >= NB * NK * NK) return;
  int b  = idx / (NK * NK);
  int rr = idx % (NK * NK);
  int k1 = rr / NK, k2 = rr % NK;
  const float* p1 = proj + ((size_t)b * NK + k1) * 48;
  const float* p2 = proj + ((size_t)b * NK + k2) * 48;
  float mx = p1[8] + p2[28];
#pragma unroll
  for (int m = 1; m < 20; ++m) mx = fmaxf(mx, p1[8 + m] + p2[28 + m]);
  float* o = out + (size_t)idx * 5;
  o[0] = mx;
#pragma unroll
  for (int r = 0; r < 4; ++r) o[1 + r] = p1[r] + p2[4 + r];
}

// ---------------------------------------------------------------------------
extern "C" void kernel_launch(void* const* d_in, const int* in_sizes, int n_in,
                              void* d_out, int out_size, void* d_ws, size_t ws_size,
                              hipStream_t stream) {
  const float* x      = (const float*)d_in[0];
  const int*   starts = (const int*)d_in[1];
  const int*   lens   = (const int*)d_in[2];
  const float* anchor = (const float*)d_in[3];
  const float* rel    = (const float*)d_in[4];
  const float* nota   = (const float*)d_in[5];
  float* out = (float*)d_out;

  char* ws = (char*)d_ws;
  float* rowdot = (float*)ws;                                    // 1.5 MB
  int*   topidx = (int*)(ws + (size_t)NB * 3 * NS * sizeof(float));
  float* proj   = (float*)(ws + (size_t)NB * 3 * NS * sizeof(float) + 4096);

  hipLaunchKernelGGL(kd_rowdots, dim3(1024), dim3(256), 0, stream, x, anchor, rowdot);
  hipLaunchKernelGGL(k3f_topk, dim3(NB), dim3(1024), 0, stream,
                     rowdot, starts, lens, topidx);
  hipLaunchKernelGGL(k4a_proj, dim3(NB * NK), dim3(256), 0, stream,
                     x, starts, lens, topidx, rel, nota, proj);
  hipLaunchKernelGGL(k4b_out, dim3((NB * NK * NK + 255) / 256), dim3(256), 0, stream,
                     proj, out);
}

// Round 13
// 40.405 us; speedup vs baseline: 3.0470x; 1.0635x over previous
//
#include <hip/hip_runtime.h>
#include <cstdint>
#include <cstddef>

#define NB 8
#define NS 4096
#define NN 2048
#define NH 768
#define NK 50

// ---------------------------------------------------------------------------
// KD: rowdot[b][s][c] = dot(x[b,s,:], anchor[c,:]). Interleaved [b][s][3]
// output. 4-deep row software pipeline (12 loads in flight/wave); per-row
// dot arithmetic and order identical to R12 -> bit-exact.
// ---------------------------------------------------------------------------
__global__ __launch_bounds__(256) void kd_rowdots(const float* __restrict__ x,
                                                  const float* __restrict__ anchor,
                                                  float* __restrict__ rowdot) {
  const int lane = threadIdx.x & 63;
  const int gw   = blockIdx.x * 4 + (threadIdx.x >> 6);   // 0..4095

  float4 a[3][3];
#pragma unroll
  for (int c = 0; c < 3; ++c)
#pragma unroll
    for (int p = 0; p < 3; ++p)
      a[c][p] = *reinterpret_cast<const float4*>(anchor + c * NH + p * 256 + lane * 4);

  const float* base = x + (size_t)gw * 8 * NH + lane * 4;

  float4 v[4][3];                           // 4-slot row ring

#define KD_LOAD(B, I)                                                         \
  {                                                                           \
    const float* s_ = base + (size_t)(I) * NH;                                \
    _Pragma("unroll")                                                         \
    for (int p = 0; p < 3; ++p)                                               \
      v[B][p] = *reinterpret_cast<const float4*>(s_ + p * 256);               \
  }
#define KD_CONS(B, I)                                                         \
  {                                                                           \
    float d0 = 0.f, d1 = 0.f, d2 = 0.f;                                       \
    _Pragma("unroll")                                                         \
    for (int p = 0; p < 3; ++p) {                                             \
      d0 += v[B][p].x * a[0][p].x + v[B][p].y * a[0][p].y +                   \
            v[B][p].z * a[0][p].z + v[B][p].w * a[0][p].w;                    \
      d1 += v[B][p].x * a[1][p].x + v[B][p].y * a[1][p].y +                   \
            v[B][p].z * a[1][p].z + v[B][p].w * a[1][p].w;                    \
      d2 += v[B][p].x * a[2][p].x + v[B][p].y * a[2][p].y +                   \
            v[B][p].z * a[2][p].z + v[B][p].w * a[2][p].w;                    \
    }                                                                         \
    _Pragma("unroll")                                                         \
    for (int o = 32; o > 0; o >>= 1) {                                        \
      d0 += __shfl_xor(d0, o);                                                \
      d1 += __shfl_xor(d1, o);                                                \
      d2 += __shfl_xor(d2, o);                                                \
    }                                                                         \
    if (lane == 0) {                                                          \
      int r = gw * 8 + (I);                                                   \
      float* o_ = rowdot + (size_t)r * 3;                                     \
      o_[0] = d0; o_[1] = d1; o_[2] = d2;                                     \
    }                                                                         \
  }

  KD_LOAD(0, 0) KD_LOAD(1, 1) KD_LOAD(2, 2) KD_LOAD(3, 3)
  KD_CONS(0, 0) KD_LOAD(0, 4)
  KD_CONS(1, 1) KD_LOAD(1, 5)
  KD_CONS(2, 2) KD_LOAD(2, 6)
  KD_CONS(3, 3) KD_LOAD(3, 7)
  KD_CONS(0, 4)
  KD_CONS(1, 5)
  KD_CONS(2, 6)
  KD_CONS(3, 7)
#undef KD_LOAD
#undef KD_CONS
}

// ---------------------------------------------------------------------------
// K3F: span scores + top-50. Radix select now EARLY-STOPS after 8 iterations
// (bits 31:16): T keeps low 16 bits zero, so the candidate set (ord >= T) is
// a superset of the exact top-50; the exhaustive rank phase then emits the
// exact top-50 in exact (score desc, idx asc) order -> selection unchanged.
// Halves the barrier-serialized phase. Scores bit-identical to R12.
// ---------------------------------------------------------------------------
__global__ __launch_bounds__(1024) void k3f_topk(const float* __restrict__ rowdot,
                                                 const int* __restrict__ starts,
                                                 const int* __restrict__ lens,
                                                 int* __restrict__ topidx) {
  const int b    = blockIdx.x;
  const int tid  = threadIdx.x;
  const int lane = tid & 63;

  __shared__ unsigned cnt[8][4];
  __shared__ unsigned long long cand[NN];
  __shared__ unsigned candcnt;

  if (tid < 32) cnt[tid >> 2][tid & 3] = 0u;
  if (tid == 32) candcnt = 0u;

  // ---- span scores (bit-identical to R12) ----
  unsigned long long key0, key1;
#pragma unroll
  for (int half = 0; half < 2; ++half) {
    const int sp = tid + half * 1024;
    const int st = starts[b * NN + sp];
    const int n  = lens[b * NN + sp] + 1;
    const float* rd = rowdot + ((size_t)b * NS + st) * 3;
    float v0[8], v1[8], v2[8];
#pragma unroll
    for (int r = 0; r < 8; ++r) {          // st+7 <= 4094 < NS: always safe
      v0[r] = rd[r * 3];
      v1[r] = rd[r * 3 + 1];
      v2[r] = rd[r * 3 + 2];
    }
    float s0 = 0.f, s1 = 0.f, s2 = 0.f;
#pragma unroll
    for (int r = 0; r < 8; ++r) {
      const bool c = r < n;
      const float t0 = s0 + v0[r], t1 = s1 + v1[r], t2 = s2 + v2[r];
      s0 = c ? t0 : s0; s1 = c ? t1 : s1; s2 = c ? t2 : s2;
    }
    float sc = fmaxf(s0, fmaxf(s1, s2)) / (float)n;
    unsigned u   = __float_as_uint(sc);
    unsigned ord = (u & 0x80000000u) ? ~u : (u | 0x80000000u);
    unsigned long long k = ((unsigned long long)ord << 32) | (unsigned)(NN - 1 - sp);
    if (half == 0) key0 = k; else key1 = k;
  }
  const unsigned ord0 = (unsigned)(key0 >> 32);
  const unsigned ord1 = (unsigned)(key1 >> 32);
  __syncthreads();

  // ---- radix-2 MSB-first select, bits 31:16 only ----
  unsigned T = 0;
  int rem = NK;
  bool a0 = true, a1 = true;
#pragma unroll
  for (int it = 0; it < 8; ++it) {
    const int bit = 30 - 2 * it;
    const int u0 = a0 ? (int)((ord0 >> bit) & 3) : -1;
    const int u1 = a1 ? (int)((ord1 >> bit) & 3) : -1;
    const unsigned c3 = __popcll(__ballot(u0 == 3)) + __popcll(__ballot(u1 == 3));
    const unsigned c2 = __popcll(__ballot(u0 == 2)) + __popcll(__ballot(u1 == 2));
    const unsigned c1 = __popcll(__ballot(u0 == 1)) + __popcll(__ballot(u1 == 1));
    if (lane == 0) {
      if (c3) atomicAdd(&cnt[it][3], c3);
      if (c2) atomicAdd(&cnt[it][2], c2);
      if (c1) atomicAdd(&cnt[it][1], c1);
    }
    __syncthreads();
    const int C3 = (int)cnt[it][3];
    const int C2 = (int)cnt[it][2];
    const int C1 = (int)cnt[it][1];
    int d;
    if (C3 >= rem)                 d = 3;
    else if (C3 + C2 >= rem)      { d = 2; rem -= C3; }
    else if (C3 + C2 + C1 >= rem) { d = 1; rem -= C3 + C2; }
    else                          { d = 0; rem -= C3 + C2 + C1; }
    T |= ((unsigned)d) << bit;
    a0 = a0 && (u0 == d);
    a1 = a1 && (u1 == d);
  }

  // ---- compact candidates (superset of exact top-50), exact rank, emit ----
  if (ord0 >= T) { unsigned p = atomicAdd(&candcnt, 1u); cand[p] = key0; }
  if (ord1 >= T) { unsigned p = atomicAdd(&candcnt, 1u); cand[p] = key1; }
  __syncthreads();
  const int M = (int)candcnt;
  for (int i = tid; i < M; i += 1024) {
    const unsigned long long ki = cand[i];
    int r = 0;
    for (int j = 0; j < M; ++j) r += (cand[j] > ki);
    if (r < NK)
      topidx[b * NK + r] = (NN - 1) - (int)(ki & 0xFFFFFFFFull);
  }
}

// ---------------------------------------------------------------------------
// K4a: projections. 400 blocks x 4 waves. [UNCHANGED = R12]
// ---------------------------------------------------------------------------
__global__ __launch_bounds__(256) void k4a_proj(const float* __restrict__ x,
                                                const int* __restrict__ starts,
                                                const int* __restrict__ lens,
                                                const int* __restrict__ topidx,
                                                const float* __restrict__ rel,
                                                const float* __restrict__ nota,
                                                float* __restrict__ proj) {
  const int blk  = blockIdx.x;              // 0..399 = b*NK + k
  const int wid  = threadIdx.x >> 6;        // 0..3
  const int lane = threadIdx.x & 63;
  const int b = blk / NK, k = blk % NK;
  const int n  = topidx[b * NK + k];
  const int st = starts[b * NN + n];
  const int nt = lens[b * NN + n] + 1;
  const float fnt = (float)nt;

  float4 e[3];
#pragma unroll
  for (int p = 0; p < 3; ++p) { e[p].x = 0.f; e[p].y = 0.f; e[p].z = 0.f; e[p].w = 0.f; }
  for (int r = 0; r < nt; ++r) {
    const float* row = x + ((size_t)b * NS + st + r) * NH + lane * 4;
#pragma unroll
    for (int p = 0; p < 3; ++p) {
      float4 v = *reinterpret_cast<const float4*>(row + p * 256);
      e[p].x += v.x; e[p].y += v.y; e[p].z += v.z; e[p].w += v.w;
    }
  }
#pragma unroll
  for (int p = 0; p < 3; ++p) {
    e[p].x /= fnt; e[p].y /= fnt; e[p].z /= fnt; e[p].w /= fnt;
  }

#pragma unroll
  for (int j = 0; j < 12; ++j) {
    const int w = wid * 12 + j;
    const float* wr;
    if (w < 4)       wr = rel  + (size_t)w * (2 * NH);
    else if (w < 8)  wr = rel  + (size_t)(w - 4) * (2 * NH) + NH;
    else if (w < 28) wr = nota + (size_t)(w - 8) * (2 * NH);
    else             wr = nota + (size_t)(w - 28) * (2 * NH) + NH;
    wr += lane * 4;
    float d = 0.f;
#pragma unroll
    for (int p = 0; p < 3; ++p) {
      float4 wv = *reinterpret_cast<const float4*>(wr + p * 256);
      d += e[p].x * wv.x + e[p].y * wv.y + e[p].z * wv.z + e[p].w * wv.w;
    }
#pragma unroll
    for (int o = 32; o > 0; o >>= 1) d += __shfl_xor(d, o);
    if (lane == 0) proj[((size_t)b * NK + k) * 48 + w] = d;
  }
}

// ---------------------------------------------------------------------------
// K4b: epilogue. [UNCHANGED]
// ---------------------------------------------------------------------------
__global__ __launch_bounds__(256) void k4b_out(const float* __restrict__ proj,
                                               float* __restrict__ out) {
  int idx = blockIdx.x * 256 + threadIdx.x;
  if (idx >= NB * NK * NK) return;
  int b  = idx / (NK * NK);
  int rr = idx % (NK * NK);
  int k1 = rr / NK, k2 = rr % NK;
  const float* p1 = proj + ((size_t)b * NK + k1) * 48;
  const float* p2 = proj + ((size_t)b * NK + k2) * 48;
  float mx = p1[8] + p2[28];
#pragma unroll
  for (int m = 1; m < 20; ++m) mx = fmaxf(mx, p1[8 + m] + p2[28 + m]);
  float* o = out + (size_t)idx * 5;
  o[0] = mx;
#pragma unroll
  for (int r = 0; r < 4; ++r) o[1 + r] = p1[r] + p2[4 + r];
}

// ---------------------------------------------------------------------------
extern "C" void kernel_launch(void* const* d_in, const int* in_sizes, int n_in,
                              void* d_out, int out_size, void* d_ws, size_t ws_size,
                              hipStream_t stream) {
  const float* x      = (const float*)d_in[0];
  const int*   starts = (const int*)d_in[1];
  const int*   lens   = (const int*)d_in[2];
  const float* anchor = (const float*)d_in[3];
  const float* rel    = (const float*)d_in[4];
  const float* nota   = (const float*)d_in[5];
  float* out = (float*)d_out;

  char* ws = (char*)d_ws;
  float* rowdot = (float*)ws;                                    // 1.5 MB
  int*   topidx = (int*)(ws + (size_t)NB * 3 * NS * sizeof(float));
  float* proj   = (float*)(ws + (size_t)NB * 3 * NS * sizeof(float) + 4096);

  hipLaunchKernelGGL(kd_rowdots, dim3(1024), dim3(256), 0, stream, x, anchor, rowdot);
  hipLaunchKernelGGL(k3f_topk, dim3(NB), dim3(1024), 0, stream,
                     rowdot, starts, lens, topidx);
  hipLaunchKernelGGL(k4a_proj, dim3(NB * NK), dim3(256), 0, stream,
                     x, starts, lens, topidx, rel, nota, proj);
  hipLaunchKernelGGL(k4b_out, dim3((NB * NK * NK + 255) / 256), dim3(256), 0, stream,
                     proj, out);
}